// Round 6
// baseline (313.651 us; speedup 1.0000x reference)
//
#include <hip/hip_runtime.h>
#include <hip/hip_cooperative_groups.h>

namespace cg = cooperative_groups;

// RepulsionLoss: points [B=4, N=8192, 3] fp32 -> scalar.
// Round 6: ONE cooperative dispatch building the R3 CSR grid (count -> leader
// scan -> scatter) then querying in CELL-SORTED order (R5's regression was
// random-order queries). Neighborhoods read as 9 contiguous row-spans
// (cells x-1..x+1 are raster-contiguous), exact ring-2+ fallback, quad-shfl
// bitonic merge, one atomic per block.

#define B_    4
#define N_    8192
#define KNN_  8
#define G_    12
#define C_    (G_ * G_ * G_)   // 1728
#define CS_   (C_ + 1)
#define NBLK_ 512
#define NTHR_ 256

constexpr float GF_     = (float)G_;
constexpr float CELL_   = 1.0f / GF_;
constexpr float RADIUS_ = 0.07f;
constexpr float INV_H2_ = 1.0f / (0.03f * 0.03f);
constexpr float SCALE_  = 0.1f / (float)(B_ * N_ * KNN_);   // ALPHA / (B*N*K)

__device__ __forceinline__ int cell_coord(float x) {
    int c = (int)(x * GF_);
    return min(max(c, 0), G_ - 1);
}

__device__ __forceinline__ void insert8(float (&t)[KNN_], float v) {
#pragma unroll
    for (int k = 0; k < KNN_; k++) {
        const float lo = fminf(t[k], v);
        v = fmaxf(t[k], v);
        t[k] = lo;
    }
}

__device__ __forceinline__ void scan_span(const float4* __restrict__ sp,
                                          int j0, int j1, int s,
                                          float px, float py, float pz,
                                          float (&t)[KNN_]) {
    for (int j = j0 + s; j < j1; j += 4) {
        const float4 Q = sp[j];
        const float dx = px - Q.x, dy = py - Q.y, dz = pz - Q.z;
        const float d2 = dx * dx + dy * dy + dz * dz;
        if (d2 < t[KNN_ - 1]) insert8(t, d2);
    }
}

__global__ __launch_bounds__(NTHR_, 2) void fused_kernel(
        const float* __restrict__ pts, int* __restrict__ counts,
        int* __restrict__ cellStart, int* __restrict__ cursor,
        float4* __restrict__ sorted4, float* __restrict__ out) {
    __shared__ int   cs[CS_];        // 6.9 KB
    __shared__ int   lsum[256];
    __shared__ float bsum;
    cg::grid_group grid = cg::this_grid();

    const int tid = threadIdx.x;
    const int g   = blockIdx.x * NTHR_ + tid;   // 0..131071 == B_*N_*4... == B_*N_? (131072 = B_*N_*4? no: 4*8192=32768) g covers 131072

    // ---- phase 0: clear counts + zero out (ws re-poisoned each replay)
    if (g < B_ * C_) counts[g] = 0;
    if (g == 0) out[0] = 0.0f;
    grid.sync();

    // ---- phase 1: count (only first B_*N_ threads hold a point)
    const int gp = g;                 // point slot if < B_*N_
    int myid = -1, myb = 0; float mx = 0, my = 0, mz = 0;
    if (gp < B_ * N_) {
        myb = gp >> 13;
        mx = pts[gp * 3 + 0]; my = pts[gp * 3 + 1]; mz = pts[gp * 3 + 2];
        myid = (cell_coord(mz) * G_ + cell_coord(my)) * G_ + cell_coord(mx);
        atomicAdd(&counts[myb * C_ + myid], 1);
    }
    grid.sync();

    // ---- phase 2: leader blocks 0..3 scan their batch's 1728 counts
    if (blockIdx.x < B_) {
        const int b = blockIdx.x;
        const int* cnt = counts + b * C_;
        int vals[7], tot = 0;
        const int c0 = tid * 7;                     // 256*7 >= 1728
#pragma unroll
        for (int k = 0; k < 7; k++) {
            const int c = c0 + k;
            const int v = (c < C_) ? cnt[c] : 0;
            vals[k] = v; tot += v;
        }
        lsum[tid] = tot;
        __syncthreads();
        for (int off = 1; off < 256; off <<= 1) {
            const int v = (tid >= off) ? lsum[tid - off] : 0;
            __syncthreads();
            lsum[tid] += v;
            __syncthreads();
        }
        int run = lsum[tid] - tot;
#pragma unroll
        for (int k = 0; k < 7; k++) {
            const int c = c0 + k;
            if (c < C_) {
                cellStart[b * CS_ + c] = run;
                cursor[b * C_ + c]     = run;
                run += vals[k];
            }
        }
        if (tid == 255) cellStart[b * CS_ + C_] = N_;
    }
    grid.sync();

    // ---- phase 3: stage this block's query-batch cellStart into LDS,
    //      then scatter (overlaps the staging loads).
    const int qb = blockIdx.x >> 7;                  // query batch of this block
    for (int i = tid; i < CS_; i += NTHR_) cs[i] = cellStart[qb * CS_ + i];
    if (tid == 0) bsum = 0.0f;
    if (gp < B_ * N_) {
        const int pos = atomicAdd(&cursor[myb * C_ + myid], 1);
        sorted4[(size_t)myb * N_ + pos] = make_float4(mx, my, mz, 0.0f);
    }
    grid.sync();   // also orders the cs[] staging for this block

    // ---- phase 4: query in sorted order. 64 points/block, 4-way j-split.
    const int q = tid >> 2;
    const int s = tid & 3;
    const int i = ((blockIdx.x & 127) << 6) + q;     // sorted index in batch
    const float4* sp = sorted4 + (size_t)qb * N_;
    const float4 P = sp[i];
    const float px = P.x, py = P.y, pz = P.z;
    const int cx = cell_coord(px), cy = cell_coord(py), cz = cell_coord(pz);

    float t[KNN_];
#pragma unroll
    for (int k = 0; k < KNN_; k++) t[k] = 1e30f;

    // Phase A: 9 row-spans covering rings 0+1 (x-1..x+1 raster-contiguous).
    const int xa = max(cx - 1, 0), xb1 = min(cx + 1, G_ - 1);
#pragma unroll
    for (int n = 0; n < 9; n++) {
        const int dz = n / 3 - 1, dy = n % 3 - 1;
        const int z = cz + dz, y = cy + dy;
        if ((unsigned)z >= G_ || (unsigned)y >= G_) continue;
        const int rb = (z * G_ + y) * G_;
        scan_span(sp, cs[rb + xa], cs[rb + xb1 + 1], s, px, py, pz, t);
    }

    // Conservative union bound: min of the 4 splits' 8th-best.
    float m4 = t[KNN_ - 1];
    m4 = fminf(m4, __shfl_xor(m4, 1));
    m4 = fminf(m4, __shfl_xor(m4, 2));

    // Exact fallback: ring r while ((r-1)*g)^2 < min(m4, own t7).
    for (int r = 2; r < G_; r++) {
        const float dmin = (float)(r - 1) * CELL_;
        if (dmin * dmin >= fminf(m4, t[KNN_ - 1])) break;
        for (int dz = -r; dz <= r; ++dz) {
            const int z = cz + dz; if ((unsigned)z >= G_) continue;
            const bool zface = (dz == -r) | (dz == r);
            for (int dy = -r; dy <= r; ++dy) {
                const int y = cy + dy; if ((unsigned)y >= G_) continue;
                const int rb = (z * G_ + y) * G_;
                if (zface | (dy == -r) | (dy == r)) {
                    // full x-run is on the ring: one contiguous span
                    const int x0 = max(cx - r, 0), x1 = min(cx + r, G_ - 1);
                    scan_span(sp, cs[rb + x0], cs[rb + x1 + 1], s, px, py, pz, t);
                } else {
                    const int xm = cx - r, xp = cx + r;
                    if (xm >= 0)  scan_span(sp, cs[rb + xm], cs[rb + xm + 1], s, px, py, pz, t);
                    if (xp < G_)  scan_span(sp, cs[rb + xp], cs[rb + xp + 1], s, px, py, pz, t);
                }
            }
        }
    }

    // Quad merge: bitonic half-cleaner over shfl_xor(1,2) (verified R4/R5).
#pragma unroll
    for (int md = 1; md <= 2; md <<= 1) {
        float u[KNN_];
#pragma unroll
        for (int i2 = 0; i2 < KNN_; i2++)
            u[i2] = fminf(t[i2], __shfl_xor(t[KNN_ - 1 - i2], md));
#pragma unroll
        for (int d = 4; d >= 1; d >>= 1) {
#pragma unroll
            for (int i2 = 0; i2 < KNN_; i2++) {
                if ((i2 & d) == 0) {
                    const float a = u[i2], e = u[i2 + d];
                    u[i2] = fminf(a, e); u[i2 + d] = fmaxf(a, e);
                }
            }
        }
#pragma unroll
        for (int i2 = 0; i2 < KNN_; i2++) t[i2] = u[i2];
    }

    float tsum = 0.0f;
    if (s == 0) {
#pragma unroll
        for (int k = 0; k < KNN_; k++) {
            const float dm = fmaxf(t[k], 1e-12f);   // self: d2=0 -> dn=1e-6
            const float dn = sqrtf(dm);
            tsum += (RADIUS_ - dn) * __expf(-dm * INV_H2_);
        }
    }
#pragma unroll
    for (int off = 1; off < 64; off <<= 1) tsum += __shfl_xor(tsum, off);
    if ((tid & 63) == 0) atomicAdd(&bsum, tsum);
    __syncthreads();
    if (tid == 0) atomicAdd(out, bsum * SCALE_);
}

extern "C" void kernel_launch(void* const* d_in, const int* in_sizes, int n_in,
                              void* d_out, int out_size, void* d_ws, size_t ws_size,
                              hipStream_t stream) {
    const float* pts = (const float*)d_in[0];
    float*       out = (float*)d_out;

    char* ws = (char*)d_ws;
    float4* sorted4   = (float4*)(ws);                            // 524288 B
    int*    counts    = (int*)(ws + 524288);                      //  27648 B
    int*    cellStart = (int*)(ws + 524288 + 27648);              //  27664 B
    int*    cursor    = (int*)(ws + 524288 + 27648 + 27664);      //  27648 B

    void* args[6] = { (void*)&pts, (void*)&counts, (void*)&cellStart,
                      (void*)&cursor, (void*)&sorted4, (void*)&out };
    hipLaunchCooperativeKernel((const void*)fused_kernel, dim3(NBLK_), dim3(NTHR_),
                               (void**)args, 0, stream);
}

// Round 7
// 133.778 us; speedup vs baseline: 2.3446x; 2.3446x over previous
//
#include <hip/hip_runtime.h>

// RepulsionLoss: points [B=4, N=8192, 3] fp32 -> scalar.
// Round 7: non-cooperative 5-dispatch pipeline (cooperative grid.sync cost
// ~25us extra fixed + idle spin — R5/R6 evidence). CSR grid build (count ->
// wide shfl scan -> scatter), query in cell-sorted order with:
//   - 9 contiguous row-spans for rings 0+1 (x-1..x+1 raster-contiguous)
//   - 8-way j-split, 32 pts/block -> 1024 blocks (4 blocks/CU, 16 waves/CU)
//   - TRUE merged 8th-NN bound (R4-R6 used per-split bounds -> ring-2 scanned
//     for most points, ~4.5x extra work; R7 computes the true bound into a
//     TEMP copy so per-lane slice lists stay disjoint for the final merge)
//   - exact ring-2+ fallback, shfl bitonic merges, 1 atomic/wave.

#define B_    4
#define N_    8192
#define KNN_  8
#define G_    12
#define C_    (G_ * G_ * G_)   // 1728
#define CS_   (C_ + 1)

constexpr float GF_     = (float)G_;
constexpr float CELL_   = 1.0f / GF_;
constexpr float RADIUS_ = 0.07f;
constexpr float INV_H2_ = 1.0f / (0.03f * 0.03f);
constexpr float SCALE_  = 0.1f / (float)(B_ * N_ * KNN_);   // ALPHA / (B*N*K)

__device__ __forceinline__ int cell_coord(float x) {
    int c = (int)(x * GF_);
    return min(max(c, 0), G_ - 1);
}

__device__ __forceinline__ void insert8(float (&t)[KNN_], float v) {
#pragma unroll
    for (int k = 0; k < KNN_; k++) {
        const float lo = fminf(t[k], v);
        v = fmaxf(t[k], v);
        t[k] = lo;
    }
}

// 3-stage bitonic merge across the 8 lanes of a point-group: after stages
// md=1,2,4 every lane holds the sorted min-8 of the union of the 8 lists.
// ONLY valid when the 8 lane lists are disjoint candidate slices.
__device__ __forceinline__ void merge8(float (&t)[KNN_]) {
#pragma unroll
    for (int md = 1; md <= 4; md <<= 1) {
        float u[KNN_];
#pragma unroll
        for (int i2 = 0; i2 < KNN_; i2++)
            u[i2] = fminf(t[i2], __shfl_xor(t[KNN_ - 1 - i2], md));
#pragma unroll
        for (int d = 4; d >= 1; d >>= 1) {
#pragma unroll
            for (int i2 = 0; i2 < KNN_; i2++) {
                if ((i2 & d) == 0) {
                    const float a = u[i2], e = u[i2 + d];
                    u[i2] = fminf(a, e); u[i2 + d] = fmaxf(a, e);
                }
            }
        }
#pragma unroll
        for (int i2 = 0; i2 < KNN_; i2++) t[i2] = u[i2];
    }
}

__device__ __forceinline__ void scan_span(const float4* __restrict__ sp,
                                          int j0, int j1, int s,
                                          float px, float py, float pz,
                                          float (&t)[KNN_]) {
    for (int j = j0 + s; j < j1; j += 8) {
        const float4 Q = sp[j];
        const float dx = px - Q.x, dy = py - Q.y, dz = pz - Q.z;
        const float d2 = dx * dx + dy * dy + dz * dz;
        if (d2 < t[KNN_ - 1]) insert8(t, d2);
    }
}

__global__ __launch_bounds__(256) void count_kernel(const float* __restrict__ pts,
                                                    int* __restrict__ counts,
                                                    float* __restrict__ out) {
    const int g = blockIdx.x * 256 + threadIdx.x;   // 0..B*N-1
    if (g == 0) out[0] = 0.0f;                      // out re-poisoned each replay
    const int b = g >> 13;
    const float x = pts[g * 3 + 0], y = pts[g * 3 + 1], z = pts[g * 3 + 2];
    const int id = (cell_coord(z) * G_ + cell_coord(y)) * G_ + cell_coord(x);
    atomicAdd(&counts[b * C_ + id], 1);
}

// 4 blocks (one per batch): 7 cells/thread, shfl wave-scan + 4 wave partials.
__global__ __launch_bounds__(256) void scan_kernel(const int* __restrict__ counts,
                                                   int* __restrict__ cellStart,
                                                   int* __restrict__ cursor) {
    __shared__ int wsum[4];
    const int b = blockIdx.x, t = threadIdx.x;
    const int lane = t & 63, w = t >> 6;
    const int* cnt = counts + b * C_;
    int vals[7], tot = 0;
    const int c0 = t * 7;                            // 256*7 = 1792 >= 1728
#pragma unroll
    for (int k = 0; k < 7; k++) {
        const int c = c0 + k;
        const int v = (c < C_) ? cnt[c] : 0;
        vals[k] = v; tot += v;
    }
    int incl = tot;
#pragma unroll
    for (int off = 1; off < 64; off <<= 1) {
        const int v = __shfl_up(incl, off, 64);
        if (lane >= off) incl += v;
    }
    if (lane == 63) wsum[w] = incl;
    __syncthreads();
    int woff = 0;
    for (int ww = 0; ww < w; ww++) woff += wsum[ww];
    int run = woff + incl - tot;                     // exclusive base
#pragma unroll
    for (int k = 0; k < 7; k++) {
        const int c = c0 + k;
        if (c < C_) {
            cellStart[b * CS_ + c] = run;
            cursor[b * C_ + c]     = run;
            run += vals[k];
        }
    }
    if (t == 255) cellStart[b * CS_ + C_] = N_;
}

__global__ __launch_bounds__(256) void scatter_kernel(const float* __restrict__ pts,
                                                      int* __restrict__ cursor,
                                                      float4* __restrict__ sorted4) {
    const int g = blockIdx.x * 256 + threadIdx.x;
    const int b = g >> 13;
    const float x = pts[g * 3 + 0], y = pts[g * 3 + 1], z = pts[g * 3 + 2];
    const int id = (cell_coord(z) * G_ + cell_coord(y)) * G_ + cell_coord(x);
    const int pos = atomicAdd(&cursor[b * C_ + id], 1);
    sorted4[(size_t)b * N_ + pos] = make_float4(x, y, z, 0.0f);
}

// 1024 blocks: 32 sorted points/block, 8-way j-split per point.
__global__ __launch_bounds__(256, 4) void query_kernel(const float4* __restrict__ sorted4,
                                                       const int* __restrict__ cellStart,
                                                       float* __restrict__ out) {
    __shared__ int cs[CS_];              // 6.9 KB
    const int tid = threadIdx.x;
    const int b   = blockIdx.x >> 8;     // 256 blocks per batch
    const int i   = ((blockIdx.x & 255) << 5) + (tid >> 3);   // sorted index
    const int s   = tid & 7;

    for (int q = tid; q < CS_; q += 256) cs[q] = cellStart[b * CS_ + q];
    __syncthreads();

    const float4* sp = sorted4 + (size_t)b * N_;
    const float4 P = sp[i];
    const float px = P.x, py = P.y, pz = P.z;
    const int cx = cell_coord(px), cy = cell_coord(py), cz = cell_coord(pz);

    float t[KNN_];
#pragma unroll
    for (int k = 0; k < KNN_; k++) t[k] = 1e30f;

    // Phase A: rings 0+1 as 9 contiguous row-spans.
    const int xa = max(cx - 1, 0), xb = min(cx + 1, G_ - 1);
#pragma unroll
    for (int n = 0; n < 9; n++) {
        const int dz = n / 3 - 1, dy = n % 3 - 1;
        const int z = cz + dz, y = cy + dy;
        if ((unsigned)z >= G_ || (unsigned)y >= G_) continue;
        const int rb = (z * G_ + y) * G_;
        scan_span(sp, cs[rb + xa], cs[rb + xb + 1], s, px, py, pz, t);
    }

    // TRUE merged 8th-NN-so-far bound, via a temp copy (keep t as disjoint
    // slices for the final merge).
    float m;
    {
        float tmp[KNN_];
#pragma unroll
        for (int k = 0; k < KNN_; k++) tmp[k] = t[k];
        merge8(tmp);
        m = tmp[KNN_ - 1];               // uniform across the 8-lane group
    }

    // Exact fallback: scan ring r while ((r-1)*g)^2 < m. A skipped candidate
    // has d2 >= dmin^2 >= m, and some lane already holds 8 values <= m.
    for (int r = 2; r < G_; r++) {
        const float dmin = (float)(r - 1) * CELL_;
        if (dmin * dmin >= m) break;
        for (int dz = -r; dz <= r; ++dz) {
            const int z = cz + dz; if ((unsigned)z >= G_) continue;
            const bool zface = (dz == -r) | (dz == r);
            for (int dy = -r; dy <= r; ++dy) {
                const int y = cy + dy; if ((unsigned)y >= G_) continue;
                const int rb = (z * G_ + y) * G_;
                if (zface | (dy == -r) | (dy == r)) {
                    const int x0 = max(cx - r, 0), x1 = min(cx + r, G_ - 1);
                    scan_span(sp, cs[rb + x0], cs[rb + x1 + 1], s, px, py, pz, t);
                } else {
                    const int xm = cx - r, xp = cx + r;
                    if (xm >= 0) scan_span(sp, cs[rb + xm], cs[rb + xm + 1], s, px, py, pz, t);
                    if (xp < G_) scan_span(sp, cs[rb + xp], cs[rb + xp + 1], s, px, py, pz, t);
                }
            }
        }
        // refresh bound: group-min of per-lane 8th-bests (valid: that lane
        // holds 8 values <= it), combined with the standing true bound.
        float mm = t[KNN_ - 1];
        mm = fminf(mm, __shfl_xor(mm, 1));
        mm = fminf(mm, __shfl_xor(mm, 2));
        mm = fminf(mm, __shfl_xor(mm, 4));
        m = fminf(m, mm);
    }

    // Final merge of the 8 disjoint slice lists -> true top-8.
    merge8(t);

    float tsum = 0.0f;
    if (s == 0) {
#pragma unroll
        for (int k = 0; k < KNN_; k++) {
            const float dm = fmaxf(t[k], 1e-12f);   // self: d2=0 -> dn=1e-6
            const float dn = sqrtf(dm);
            tsum += (RADIUS_ - dn) * __expf(-dm * INV_H2_);
        }
    }
#pragma unroll
    for (int off = 1; off < 64; off <<= 1) tsum += __shfl_xor(tsum, off);
    if ((tid & 63) == 0) atomicAdd(out, tsum * SCALE_);
}

extern "C" void kernel_launch(void* const* d_in, const int* in_sizes, int n_in,
                              void* d_out, int out_size, void* d_ws, size_t ws_size,
                              hipStream_t stream) {
    const float* pts = (const float*)d_in[0];
    float*       out = (float*)d_out;

    char* ws = (char*)d_ws;
    float4* sorted4   = (float4*)(ws);                            // 524288 B
    int*    counts    = (int*)(ws + 524288);                      //  27648 B
    int*    cellStart = (int*)(ws + 524288 + 27648);              //  27664 B
    int*    cursor    = (int*)(ws + 524288 + 27648 + 27664);      //  27648 B

    hipMemsetAsync(counts, 0, B_ * C_ * sizeof(int), stream);
    count_kernel  <<<B_ * N_ / 256, 256, 0, stream>>>(pts, counts, out);
    scan_kernel   <<<B_,            256, 0, stream>>>(counts, cellStart, cursor);
    scatter_kernel<<<B_ * N_ / 256, 256, 0, stream>>>(pts, cursor, sorted4);
    query_kernel  <<<B_ * N_ / 32,  256, 0, stream>>>(sorted4, cellStart, out);
}

// Round 8
// 122.476 us; speedup vs baseline: 2.5609x; 1.0923x over previous
//
#include <hip/hip_runtime.h>

// RepulsionLoss: points [B=4, N=8192, 3] fp32 -> scalar.
// Round 8: CSR grid build (5 dispatches as R7) + streaming query:
//   - 2-way split only (R1->R3->R7 evidence: per-lane trip count is the
//     efficiency dial; 8-way split made span loops ~1.8 trips -> no load
//     pipelining, VALUBusy 11%. 2-way gives ~7 trips/span.)
//   - no LDS, no __syncthreads in query: cellStart is L1-resident (6.9KB
//     shared by all blocks); 18 span bounds loaded up-front into registers.
//   - true merged bound (R7), exact ring-2+ fallback, 1 atomic/wave.

#define B_    4
#define N_    8192
#define KNN_  8
#define G_    12
#define C_    (G_ * G_ * G_)   // 1728
#define CS_   (C_ + 1)

constexpr float GF_     = (float)G_;
constexpr float CELL_   = 1.0f / GF_;
constexpr float RADIUS_ = 0.07f;
constexpr float INV_H2_ = 1.0f / (0.03f * 0.03f);
constexpr float SCALE_  = 0.1f / (float)(B_ * N_ * KNN_);   // ALPHA / (B*N*K)

__device__ __forceinline__ int cell_coord(float x) {
    int c = (int)(x * GF_);
    return min(max(c, 0), G_ - 1);
}

__device__ __forceinline__ void insert8(float (&t)[KNN_], float v) {
#pragma unroll
    for (int k = 0; k < KNN_; k++) {
        const float lo = fminf(t[k], v);
        v = fmaxf(t[k], v);
        t[k] = lo;
    }
}

// One bitonic stage across lane pairs (xor 1): both lanes end with the sorted
// min-8 of the union of their two lists. Valid only for disjoint slice lists.
__device__ __forceinline__ void merge2(float (&t)[KNN_]) {
    float u[KNN_];
#pragma unroll
    for (int i2 = 0; i2 < KNN_; i2++)
        u[i2] = fminf(t[i2], __shfl_xor(t[KNN_ - 1 - i2], 1));
#pragma unroll
    for (int d = 4; d >= 1; d >>= 1) {
#pragma unroll
        for (int i2 = 0; i2 < KNN_; i2++) {
            if ((i2 & d) == 0) {
                const float a = u[i2], e = u[i2 + d];
                u[i2] = fminf(a, e); u[i2 + d] = fmaxf(a, e);
            }
        }
    }
#pragma unroll
    for (int i2 = 0; i2 < KNN_; i2++) t[i2] = u[i2];
}

__device__ __forceinline__ void scan_span(const float4* __restrict__ sp,
                                          int j0, int j1, int s,
                                          float px, float py, float pz,
                                          float (&t)[KNN_]) {
    for (int j = j0 + s; j < j1; j += 2) {
        const float4 Q = sp[j];
        const float dx = px - Q.x, dy = py - Q.y, dz = pz - Q.z;
        const float d2 = dx * dx + dy * dy + dz * dz;
        if (d2 < t[KNN_ - 1]) insert8(t, d2);
    }
}

__global__ __launch_bounds__(256) void count_kernel(const float* __restrict__ pts,
                                                    int* __restrict__ counts,
                                                    float* __restrict__ out) {
    const int g = blockIdx.x * 256 + threadIdx.x;   // 0..B*N-1
    if (g == 0) out[0] = 0.0f;                      // out re-poisoned each replay
    const int b = g >> 13;
    const float x = pts[g * 3 + 0], y = pts[g * 3 + 1], z = pts[g * 3 + 2];
    const int id = (cell_coord(z) * G_ + cell_coord(y)) * G_ + cell_coord(x);
    atomicAdd(&counts[b * C_ + id], 1);
}

// 4 blocks (one per batch): 7 cells/thread, shfl wave-scan + 4 wave partials.
__global__ __launch_bounds__(256) void scan_kernel(const int* __restrict__ counts,
                                                   int* __restrict__ cellStart,
                                                   int* __restrict__ cursor) {
    __shared__ int wsum[4];
    const int b = blockIdx.x, t = threadIdx.x;
    const int lane = t & 63, w = t >> 6;
    const int* cnt = counts + b * C_;
    int vals[7], tot = 0;
    const int c0 = t * 7;                            // 256*7 = 1792 >= 1728
#pragma unroll
    for (int k = 0; k < 7; k++) {
        const int c = c0 + k;
        const int v = (c < C_) ? cnt[c] : 0;
        vals[k] = v; tot += v;
    }
    int incl = tot;
#pragma unroll
    for (int off = 1; off < 64; off <<= 1) {
        const int v = __shfl_up(incl, off, 64);
        if (lane >= off) incl += v;
    }
    if (lane == 63) wsum[w] = incl;
    __syncthreads();
    int woff = 0;
    for (int ww = 0; ww < w; ww++) woff += wsum[ww];
    int run = woff + incl - tot;                     // exclusive base
#pragma unroll
    for (int k = 0; k < 7; k++) {
        const int c = c0 + k;
        if (c < C_) {
            cellStart[b * CS_ + c] = run;
            cursor[b * C_ + c]     = run;
            run += vals[k];
        }
    }
    if (t == 255) cellStart[b * CS_ + C_] = N_;
}

__global__ __launch_bounds__(256) void scatter_kernel(const float* __restrict__ pts,
                                                      int* __restrict__ cursor,
                                                      float4* __restrict__ sorted4) {
    const int g = blockIdx.x * 256 + threadIdx.x;
    const int b = g >> 13;
    const float x = pts[g * 3 + 0], y = pts[g * 3 + 1], z = pts[g * 3 + 2];
    const int id = (cell_coord(z) * G_ + cell_coord(y)) * G_ + cell_coord(x);
    const int pos = atomicAdd(&cursor[b * C_ + id], 1);
    sorted4[(size_t)b * N_ + pos] = make_float4(x, y, z, 0.0f);
}

// 512 blocks x 128 threads: 64 sorted points/block, 2-way j-split.
__global__ __launch_bounds__(128) void query_kernel(const float4* __restrict__ sorted4,
                                                    const int* __restrict__ cellStart,
                                                    float* __restrict__ out) {
    const int tid = threadIdx.x;
    const int b   = blockIdx.x >> 7;                         // 128 blocks/batch
    const int i   = ((blockIdx.x & 127) << 6) + (tid >> 1);  // sorted index
    const int s   = tid & 1;

    const int*    csg = cellStart + b * CS_;
    const float4* sp  = sorted4 + (size_t)b * N_;
    const float4 P = sp[i];
    const float px = P.x, py = P.y, pz = P.z;
    const int cx = cell_coord(px), cy = cell_coord(py), cz = cell_coord(pz);

    // Up-front span bounds for rings 0+1: 9 rows, x-1..x+1 raster-contiguous.
    // All 18 loads independent -> in flight together (L1-resident table).
    const int xa = max(cx - 1, 0), xb = min(cx + 1, G_ - 1);
    int j0[9], j1[9];
#pragma unroll
    for (int n = 0; n < 9; n++) {
        const int dz = n / 3 - 1, dy = n % 3 - 1;
        const int z = cz + dz, y = cy + dy;
        if ((unsigned)z < G_ && (unsigned)y < G_) {
            const int rb = (z * G_ + y) * G_;
            j0[n] = csg[rb + xa]; j1[n] = csg[rb + xb + 1];
        } else { j0[n] = 0; j1[n] = 0; }
    }

    float t[KNN_];
#pragma unroll
    for (int k = 0; k < KNN_; k++) t[k] = 1e30f;

#pragma unroll
    for (int n = 0; n < 9; n++)
        scan_span(sp, j0[n], j1[n], s, px, py, pz, t);

    // True merged 8th-NN bound via temp copy (t stays disjoint slices).
    float m;
    {
        float tmp[KNN_];
#pragma unroll
        for (int k = 0; k < KNN_; k++) tmp[k] = t[k];
        merge2(tmp);
        m = tmp[KNN_ - 1];
    }

    // Exact fallback: ring r while ((r-1)*g)^2 < m. Skipped candidate d2 >=
    // dmin^2 >= m and 8 union values <= m already held -> exact.
    for (int r = 2; r < G_; r++) {
        const float dmin = (float)(r - 1) * CELL_;
        if (dmin * dmin >= m) break;
        for (int dz = -r; dz <= r; ++dz) {
            const int z = cz + dz; if ((unsigned)z >= G_) continue;
            const bool zface = (dz == -r) | (dz == r);
            for (int dy = -r; dy <= r; ++dy) {
                const int y = cy + dy; if ((unsigned)y >= G_) continue;
                const int rb = (z * G_ + y) * G_;
                if (zface | (dy == -r) | (dy == r)) {
                    const int x0 = max(cx - r, 0), x1 = min(cx + r, G_ - 1);
                    scan_span(sp, csg[rb + x0], csg[rb + x1 + 1], s, px, py, pz, t);
                } else {
                    const int xm = cx - r, xp = cx + r;
                    if (xm >= 0) scan_span(sp, csg[rb + xm], csg[rb + xm + 1], s, px, py, pz, t);
                    if (xp < G_) scan_span(sp, csg[rb + xp], csg[rb + xp + 1], s, px, py, pz, t);
                }
            }
        }
        float mm = fminf(t[KNN_ - 1], __shfl_xor(t[KNN_ - 1], 1));
        m = fminf(m, mm);
    }

    merge2(t);   // final exact top-8 (disjoint slices)

    float tsum = 0.0f;
    if (s == 0) {
#pragma unroll
        for (int k = 0; k < KNN_; k++) {
            const float dm = fmaxf(t[k], 1e-12f);   // self: d2=0 -> dn=1e-6
            const float dn = sqrtf(dm);
            tsum += (RADIUS_ - dn) * __expf(-dm * INV_H2_);
        }
    }
#pragma unroll
    for (int off = 1; off < 64; off <<= 1) tsum += __shfl_xor(tsum, off);
    if ((tid & 63) == 0) atomicAdd(out, tsum * SCALE_);
}

extern "C" void kernel_launch(void* const* d_in, const int* in_sizes, int n_in,
                              void* d_out, int out_size, void* d_ws, size_t ws_size,
                              hipStream_t stream) {
    const float* pts = (const float*)d_in[0];
    float*       out = (float*)d_out;

    char* ws = (char*)d_ws;
    float4* sorted4   = (float4*)(ws);                            // 524288 B
    int*    counts    = (int*)(ws + 524288);                      //  27648 B
    int*    cellStart = (int*)(ws + 524288 + 27648);              //  27664 B
    int*    cursor    = (int*)(ws + 524288 + 27648 + 27664);      //  27648 B

    hipMemsetAsync(counts, 0, B_ * C_ * sizeof(int), stream);
    count_kernel  <<<B_ * N_ / 256, 256, 0, stream>>>(pts, counts, out);
    scan_kernel   <<<B_,            256, 0, stream>>>(counts, cellStart, cursor);
    scatter_kernel<<<B_ * N_ / 256, 256, 0, stream>>>(pts, cursor, sorted4);
    query_kernel  <<<B_ * N_ / 64,  128, 0, stream>>>(sorted4, cellStart, out);
}